// Round 3
// baseline (130.628 us; speedup 1.0000x reference)
//
#include <hip/hip_runtime.h>
#include <hip/hip_bf16.h>

typedef __bf16 bf16x2_t __attribute__((ext_vector_type(2)));
typedef __bf16 bf16x8_t __attribute__((ext_vector_type(8)));
typedef float f32x4 __attribute__((ext_vector_type(4)));

#define BATCH   8
#define LENGTH  4096
#define KHALF   128
#define MTOT    (BATCH*LENGTH)
#define NCHUNK  128

// 16B-chunk XOR swizzle: chunk index ^ (row & 7). Involution; keeps b128 frag
// reads and bf16x2 scan accesses at <=2-way bank conflict with ZERO padding.
#define SWZ(ch, row) ((ch) ^ ((row) & 7))

// ---------------- transpose B, C to bf16 (round-0 proven version) ----------------
__global__ __launch_bounds__(256) void transpose_bc(
    const float* __restrict__ Bsrc, const float* __restrict__ Csrc,
    __bf16* __restrict__ BT, __bf16* __restrict__ CT) {
  const float* src = blockIdx.y ? Csrc : Bsrc;
  __bf16* dst      = blockIdx.y ? CT   : BT;
  int n  = blockIdx.x;
  int kk = threadIdx.x;
  dst[n * 256 + kk] = (__bf16)src[kk * 256 + n];
}

// ---------------- GEMM1: uB = u @ B (32x256 tile), fused chunk-partial scan ----
// 1024 blocks -> 4 blocks/CU resident. Scan: UNSPLIT serial-32, 128 threads
// (round-0 math verbatim). Mmid written as canary (true S0 at j==15, unread).
__global__ __launch_bounds__(256, 4) void gemm1_fused(
    const float* __restrict__ u, const __bf16* __restrict__ BT,
    const float* __restrict__ Aarr,
    __bf16* __restrict__ uB, float2* __restrict__ P, float2* __restrict__ Mmid) {
  __shared__ __align__(16) __bf16 sA[32 * 256];   // 16 KB

  const int tid  = threadIdx.x;
  const int lane = tid & 63;
  const int wave = tid >> 6;          // wave = column group (0..3)
  const int m_l  = lane & 15, quad = lane >> 4;
  const int m0   = blockIdx.x * 32;
  const int b    = m0 >> 12;
  const int chg  = (m0 & 4095) >> 5;  // chunk index within batch

  // stage u (fp32 -> bf16), swizzled 16B chunks; u read exactly once
#pragma unroll
  for (int i = 0; i < 4; ++i) {
    int s   = tid + i * 256;          // 0..1023 chunks of 8 cols
    int row = s >> 5, ch = s & 31;
    const float4* g = (const float4*)(u + (size_t)(m0 + row) * 256 + ch * 8);
    float4 a = g[0], c = g[1];
    bf16x8_t v;
    v[0]=(__bf16)a.x; v[1]=(__bf16)a.y; v[2]=(__bf16)a.z; v[3]=(__bf16)a.w;
    v[4]=(__bf16)c.x; v[5]=(__bf16)c.y; v[6]=(__bf16)c.z; v[7]=(__bf16)c.w;
    *(bf16x8_t*)&sA[row * 256 + SWZ(ch, row) * 8] = v;
  }
  __syncthreads();

  f32x4 acc[2][4];
#pragma unroll
  for (int mi = 0; mi < 2; ++mi)
#pragma unroll
    for (int ni = 0; ni < 4; ++ni)
#pragma unroll
      for (int r = 0; r < 4; ++r) acc[mi][ni][r] = 0.f;

#pragma unroll
  for (int kc8 = 0; kc8 < 8; ++kc8) {     // NO barriers in K-loop
    bf16x8_t af[2], bfr[4];
#pragma unroll
    for (int mi = 0; mi < 2; ++mi) {
      int row = mi * 16 + m_l;
      int c   = kc8 * 4 + quad;
      af[mi] = *(const bf16x8_t*)&sA[row * 256 + SWZ(c, row) * 8];
    }
#pragma unroll
    for (int ni = 0; ni < 4; ++ni) {
      int n = wave * 64 + ni * 16 + m_l;
      bfr[ni] = *(const bf16x8_t*)(BT + (size_t)n * 256 + kc8 * 32 + quad * 8);
    }
#pragma unroll
    for (int mi = 0; mi < 2; ++mi)
#pragma unroll
      for (int ni = 0; ni < 4; ++ni)
        acc[mi][ni] = __builtin_amdgcn_mfma_f32_16x16x32_bf16(af[mi], bfr[ni], acc[mi][ni], 0, 0, 0);
  }
  __syncthreads();   // done reading sA; reuse as output stash

  // stash bf16 32x256 tile into LDS (swizzled)
  __bf16* sT = sA;
#pragma unroll
  for (int mi = 0; mi < 2; ++mi)
#pragma unroll
    for (int ni = 0; ni < 4; ++ni)
#pragma unroll
      for (int r = 0; r < 4; ++r) {
        int row = mi * 16 + quad * 4 + r;
        int col = wave * 64 + ni * 16 + m_l;
        sT[row * 256 + SWZ(col >> 3, row) * 8 + (col & 7)] = (__bf16)acc[mi][ni][r];
      }
  __syncthreads();

  // coalesced uB write from LDS
#pragma unroll
  for (int i = 0; i < 4; ++i) {
    int s   = tid + i * 256;
    int row = s >> 5, ch = s & 31;
    *(bf16x8_t*)(uB + (size_t)(m0 + row) * 256 + ch * 8) =
        *(const bf16x8_t*)&sT[row * 256 + SWZ(ch, row) * 8];
  }

  // UNSPLIT scan_partial: 128 threads, serial length 32 (round-0 math).
  // Mid-state (after 16 steps) = S0, written to Mmid as canary / future use.
  if (tid < 128) {
    int k    = tid;
    float cc = Aarr[4 * k], sv = Aarr[4 * k + 1];
    float hr = 0.f, hi = 0.f, m_r = 0.f, m_i = 0.f;
#pragma unroll 8
    for (int j = 0; j < 32; ++j) {
      bf16x2_t v2 = *(const bf16x2_t*)&sT[j * 256 + SWZ(k >> 2, j) * 8 + ((2 * k) & 7)];
      float t = fmaf(hr, cc, fmaf(-hi, sv, (float)v2[0]));
      hi      = fmaf(hr, sv, fmaf( hi, cc, (float)v2[1]));
      hr = t;
      if (j == 15) { m_r = hr; m_i = hi; }
    }
    size_t idx = ((size_t)b * NCHUNK + chg) * KHALF + k;
    P[idx]    = make_float2(hr, hi);
    Mmid[idx] = make_float2(m_r, m_i);
  }
}

// ---------------- wave-parallel carry: one wave per (b,k), Kogge-Stone ----------------
__global__ __launch_bounds__(256) void scan_carry2(
    const float* __restrict__ Aarr, const float* __restrict__ x0,
    const float2* __restrict__ P, float2* __restrict__ H,
    float* __restrict__ state_out) {
  const int lane = threadIdx.x & 63;
  const int wv   = threadIdx.x >> 6;
  const int p    = blockIdx.x * 4 + wv;   // 0..1023 (b,k) pairs
  const int b    = p >> 7, k = p & 127;
  const float cc = Aarr[4 * k], sv = Aarr[4 * k + 1];

  // w32 = w^32 via 5 squarings
  float wr = cc, wi = sv;
#pragma unroll
  for (int i = 0; i < 5; ++i) { float nr = wr*wr - wi*wi; wi = 2.f*wr*wi; wr = nr; }
  // W[s] = w64^(2^s), s=0..5
  float Wr[6], Wi[6];
  Wr[0] = wr*wr - wi*wi; Wi[0] = 2.f*wr*wi;
#pragma unroll
  for (int s = 1; s < 6; ++s) { Wr[s] = Wr[s-1]*Wr[s-1] - Wi[s-1]*Wi[s-1]; Wi[s] = 2.f*Wr[s-1]*Wi[s-1]; }

  float2 P0 = P[((size_t)b * NCHUNK + 2 * lane)     * KHALF + k];
  float2 P1 = P[((size_t)b * NCHUNK + 2 * lane + 1) * KHALF + k];
  // pair combine: q = w32*P0 + P1  (segment scale w64)
  float qr = fmaf(wr, P0.x, fmaf(-wi, P0.y, P1.x));
  float qi = fmaf(wr, P0.y, fmaf( wi, P0.x, P1.y));
  // inclusive scan over lanes
  float Sr = qr, Si = qi;
#pragma unroll
  for (int s = 0; s < 6; ++s) {
    float tr = __shfl_up(Sr, 1 << s, 64);
    float ti = __shfl_up(Si, 1 << s, 64);
    if (lane >= (1 << s)) {
      float nSr = fmaf(Wr[s], tr, fmaf(-Wi[s], ti, Sr));
      float nSi = fmaf(Wr[s], ti, fmaf( Wi[s], tr, Si));
      Sr = nSr; Si = nSi;
    }
  }
  float Ar = __shfl_up(Sr, 1, 64), Ai = __shfl_up(Si, 1, 64);
  if (lane == 0) { Ar = 0.f; Ai = 0.f; }
  // pL = w64^lane
  float pr = 1.f, pi = 0.f;
#pragma unroll
  for (int s = 0; s < 6; ++s)
    if ((lane >> s) & 1) { float nr = pr*Wr[s] - pi*Wi[s]; pi = pr*Wi[s] + pi*Wr[s]; pr = nr; }

  float x0r = x0[b * 256 + 2 * k], x0i = x0[b * 256 + 2 * k + 1];
  float H0r = fmaf(pr, x0r, fmaf(-pi, x0i, Ar));
  float H0i = fmaf(pr, x0i, fmaf( pi, x0r, Ai));
  H[((size_t)b * NCHUNK + 2 * lane) * KHALF + k] = make_float2(H0r, H0i);
  float H1r = fmaf(wr, H0r, fmaf(-wi, H0i, P0.x));
  float H1i = fmaf(wr, H0i, fmaf( wi, H0r, P0.y));
  H[((size_t)b * NCHUNK + 2 * lane + 1) * KHALF + k] = make_float2(H1r, H1i);
  if (lane == 63) {
    state_out[b * 256 + 2 * k]     = fmaf(wr, H1r, fmaf(-wi, H1i, P1.x));
    state_out[b * 256 + 2 * k + 1] = fmaf(wr, H1i, fmaf( wi, H1r, P1.y));
  }
}

// ---------------- GEMM2: y = X @ C (32x256 tile), UNSPLIT replay in-LDS ------------
__global__ __launch_bounds__(256, 4) void gemm2_fused(
    const __bf16* __restrict__ uB, const float* __restrict__ Aarr,
    const float2* __restrict__ H, const float2* __restrict__ Mmid,
    const __bf16* __restrict__ CT, float* __restrict__ Y) {
  __shared__ __align__(16) __bf16 sX[32 * 256];   // 16 KB

  const int tid  = threadIdx.x;
  const int lane = tid & 63;
  const int wave = tid >> 6;
  const int m_l  = lane & 15, quad = lane >> 4;
  const int m0   = blockIdx.x * 32;
  const int b    = m0 >> 12;
  const int chg  = (m0 & 4095) >> 5;

  // reg-staged uB -> sX (swizzled) — proven round-0 pattern
#pragma unroll
  for (int i = 0; i < 4; ++i) {
    int s   = tid + i * 256;
    int row = s >> 5, ch = s & 31;
    *(bf16x8_t*)&sX[row * 256 + SWZ(ch, row) * 8] =
        *(const bf16x8_t*)(uB + (size_t)(m0 + row) * 256 + ch * 8);
  }
  __syncthreads();

  // UNSPLIT in-LDS scan replay: 128 threads, serial length 32 (round-0 math)
  if (tid < 128) {
    int k    = tid;
    float cc = Aarr[4 * k], sv = Aarr[4 * k + 1];
    float2 hH = H[((size_t)b * NCHUNK + chg) * KHALF + k];
    float hr = hH.x, hi = hH.y;
#pragma unroll 8
    for (int j = 0; j < 32; ++j) {
      int ix  = j * 256 + SWZ(k >> 2, j) * 8 + ((2 * k) & 7);
      bf16x2_t v2 = *(const bf16x2_t*)&sX[ix];
      float t = fmaf(hr, cc, fmaf(-hi, sv, (float)v2[0]));
      hi      = fmaf(hr, sv, fmaf( hi, cc, (float)v2[1]));
      hr = t;
      bf16x2_t o; o[0] = (__bf16)hr; o[1] = (__bf16)hi;
      *(bf16x2_t*)&sX[ix] = o;
    }
  }
  __syncthreads();

  f32x4 acc[2][4];
#pragma unroll
  for (int mi = 0; mi < 2; ++mi)
#pragma unroll
    for (int ni = 0; ni < 4; ++ni)
#pragma unroll
      for (int r = 0; r < 4; ++r) acc[mi][ni][r] = 0.f;

#pragma unroll
  for (int kc8 = 0; kc8 < 8; ++kc8) {     // barrier-free K-loop
    bf16x8_t af[2], bfr[4];
#pragma unroll
    for (int mi = 0; mi < 2; ++mi) {
      int row = mi * 16 + m_l;
      int c   = kc8 * 4 + quad;
      af[mi] = *(const bf16x8_t*)&sX[row * 256 + SWZ(c, row) * 8];
    }
#pragma unroll
    for (int ni = 0; ni < 4; ++ni) {
      int n = wave * 64 + ni * 16 + m_l;
      bfr[ni] = *(const bf16x8_t*)(CT + (size_t)n * 256 + kc8 * 32 + quad * 8);
    }
#pragma unroll
    for (int mi = 0; mi < 2; ++mi)
#pragma unroll
      for (int ni = 0; ni < 4; ++ni)
        acc[mi][ni] = __builtin_amdgcn_mfma_f32_16x16x32_bf16(af[mi], bfr[ni], acc[mi][ni], 0, 0, 0);
  }

#pragma unroll
  for (int mi = 0; mi < 2; ++mi)
#pragma unroll
    for (int ni = 0; ni < 4; ++ni)
#pragma unroll
      for (int r = 0; r < 4; ++r) {
        int row = m0 + mi * 16 + quad * 4 + r;
        int col = wave * 64 + ni * 16 + m_l;
        Y[(size_t)row * 256 + col] = acc[mi][ni][r];
      }
}

extern "C" void kernel_launch(void* const* d_in, const int* in_sizes, int n_in,
                              void* d_out, int out_size, void* d_ws, size_t ws_size,
                              hipStream_t stream) {
  const float* u  = (const float*)d_in[0];
  const float* x0 = (const float*)d_in[1];
  const float* A  = (const float*)d_in[2];
  const float* B  = (const float*)d_in[3];
  const float* C  = (const float*)d_in[4];

  float* y         = (float*)d_out;
  float* state_out = y + (size_t)MTOT * 256;

  char* ws = (char*)d_ws;
  __bf16* BT = (__bf16*)ws;  ws += 256 * 256 * 2;
  __bf16* CT = (__bf16*)ws;  ws += 256 * 256 * 2;
  __bf16* uB = (__bf16*)ws;  ws += (size_t)MTOT * 256 * 2;
  float2* P  = (float2*)ws;  ws += (size_t)BATCH * NCHUNK * KHALF * sizeof(float2);
  float2* H  = (float2*)ws;  ws += (size_t)BATCH * NCHUNK * KHALF * sizeof(float2);
  float2* M  = (float2*)ws;  ws += (size_t)BATCH * NCHUNK * KHALF * sizeof(float2);

  transpose_bc<<<dim3(256, 2), 256, 0, stream>>>(B, C, BT, CT);
  gemm1_fused<<<dim3(MTOT / 32), 256, 0, stream>>>(u, BT, A, uB, P, M);
  scan_carry2<<<dim3(256), 256, 0, stream>>>(A, x0, P, H, state_out);
  gemm2_fused<<<dim3(MTOT / 32), 256, 0, stream>>>(uB, A, H, M, CT, y);
}